// Round 9
// baseline (142.787 us; speedup 1.0000x reference)
//
#include <hip/hip_runtime.h>
#include <hip/hip_bf16.h>

#define M_PTS 16384
#define N_SPT 16384
#define DIM   64
#define NSL   16                 // n-slices
#define SLN   (N_SPT / NSL)      // 1024 n-rows per slice
#define TSTEPS (SLN / 16)        // 64 MFMA steps per wave
#define MBLK  128                // m-rows per block (4 waves x 32)

typedef __attribute__((ext_vector_type(8))) short bf16x8;
typedef __attribute__((ext_vector_type(4))) float f32x4;

#define LOG2E 1.4426950408889634f

__device__ __forceinline__ unsigned short f32_bf16_rne(float f) {
  unsigned int x = __float_as_uint(f);
  x = x + 0x7fffu + ((x >> 16) & 1u);
  return (unsigned short)(x >> 16);
}
__device__ __forceinline__ float bf16_f32(unsigned short u) {
  return __uint_as_float(((unsigned int)u) << 16);
}

// Prep (unchanged, known-good):
//  points : store p~ = bf16(scale * p); Em = exp2(-|p~|^2/(2*scale))
//  spatial: store s~ = bf16(s); En = w * exp2(-|s~|^2 * scale/2)
// Em*En*exp2(p~ . s~) == exact Gaussian of the rounded points.
__global__ __launch_bounds__(256) void kde_prep(
    const float* __restrict__ pts, const float* __restrict__ spt,
    const float* __restrict__ w, const float* __restrict__ bw,
    unsigned short* __restrict__ ptsb, unsigned short* __restrict__ spb,
    float* __restrict__ Em, float* __restrict__ En) {
  const float b = bw[0];
  const float scale = LOG2E / (b * b);
  const float c1 = 0.5f * scale;
  const float invc = (b * b) / (2.0f * LOG2E);
  const int tid = threadIdx.x;
  const bool isP = blockIdx.x < (M_PTS / 16);
  const int r0 = isP ? (blockIdx.x * 16) : ((blockIdx.x - M_PTS / 16) * 16);
  const float* __restrict__ src = isP ? pts : spt;
  unsigned short* __restrict__ dst = isP ? ptsb : spb;

  size_t off = (size_t)r0 * DIM + (size_t)tid * 4;
  float4 v = *reinterpret_cast<const float4*>(src + off);
  if (isP) { v.x *= scale; v.y *= scale; v.z *= scale; v.w *= scale; }
  ushort4 u;
  u.x = f32_bf16_rne(v.x); u.y = f32_bf16_rne(v.y);
  u.z = f32_bf16_rne(v.z); u.w = f32_bf16_rne(v.w);
  float ax = bf16_f32(u.x), ay = bf16_f32(u.y);
  float az = bf16_f32(u.z), aw = bf16_f32(u.w);
  float sq = ax * ax + ay * ay + az * az + aw * aw;
  *reinterpret_cast<ushort4*>(dst + off) = u;

  sq += __shfl_xor(sq, 1);
  sq += __shfl_xor(sq, 2);
  sq += __shfl_xor(sq, 4);
  sq += __shfl_xor(sq, 8);
  if ((tid & 15) == 0) {
    int row = r0 + (tid >> 4);
    if (isP) Em[row] = exp2f(-sq * invc);
    else     En[row] = w[row] * exp2f(-sq * c1);
  }
}

// Main v10 = v9 WITHOUT the __launch_bounds__ min-waves cap.
// Session rule (3/3 fail-with-cap vs 5/5 pass-without): the min-waves arg
// causes corruption under this harness whenever it constrains allocation --
// never use it. v9's math is a mechanical halving of the proven v2/v8 tile
// (indices re-audited). Halved tile (32m x 16n per step per wave): raw live
// set ~56 regs, so natural allocation should land under the 64-VGPR
// occupancy cliff (m69: waves/SIMD steps at vgpr={64,128,256}; v8's 68 sat
// just above it). 2048 blocks x 4 waves -> 8 blocks/CU -> 8 waves/SIMD,
// doubling resident TLP; VALU+TRANS busy-time is invariant ~28.5us across
// all prior variants, and wall = work / issue-density, so doubled residency
// is the one untested lever.
__global__ __launch_bounds__(256) void kde_main(
    const unsigned short* __restrict__ ptsb,
    const unsigned short* __restrict__ spb,
    const float* __restrict__ En,
    float* __restrict__ partials) {
  __shared__ float lden[SLN];  // 4 KB, read-only after one barrier

  const int tid = threadIdx.x;
  const int lane = tid & 63;
  const int wave = tid >> 6;
  const int lr = lane & 15;   // tile row (A) / tile col (B)
  const int lg = lane >> 4;   // k-group

  const int lid = blockIdx.x;
  const int s = lid >> 7;     // 16 slices; 128 consecutive blocks share one
  const int mb = lid & 127;   //  spb slice (128 KB, L2-resident)
  const int mbase = mb * MBLK + wave * 32;

#pragma unroll
  for (int k = 0; k < SLN / 256; ++k)
    lden[tid + k * 256] = En[s * SLN + tid + k * 256];

  // A fragments (read once; 16 VGPRs).
  bf16x8 a[2][2];
#pragma unroll
  for (int t = 0; t < 2; ++t)
#pragma unroll
    for (int h = 0; h < 2; ++h)
      a[t][h] = *reinterpret_cast<const bf16x8*>(
          ptsb + (size_t)(mbase + t * 16 + lr) * DIM + h * 32 + lg * 8);

  __syncthreads();  // lden ready; no further barriers

  // Per-lane B pointer: step st fragment b0 at st*2048 + lr*128 + lg*16,
  // b1 at +64 bytes.
  const char* bptr =
      (const char*)(spb + (size_t)s * SLN * DIM) + lr * 128 + lg * 16;
  const float* enr = lden + lr;

  const f32x4 kz = {0.0f, 0.0f, 0.0f, 0.0f};  // shared C-init quad
  float sum[2][4] = {{0.0f, 0.0f, 0.0f, 0.0f}, {0.0f, 0.0f, 0.0f, 0.0f}};
  f32x4 cA[2], cB[2];

#define MS(C, B0, B1)                                                        \
  {                                                                          \
    _Pragma("unroll") for (int t = 0; t < 2; ++t) {                          \
      C[t] = __builtin_amdgcn_mfma_f32_16x16x32_bf16(a[t][0], B0, kz,        \
                                                     0, 0, 0);               \
      C[t] = __builtin_amdgcn_mfma_f32_16x16x32_bf16(a[t][1], B1, C[t],      \
                                                     0, 0, 0);               \
    }                                                                        \
  }

#define FIN(C, EN)                                                           \
  {                                                                          \
    float en = (EN);                                                         \
    _Pragma("unroll") for (int t = 0; t < 2; ++t) {                          \
      _Pragma("unroll") for (int rr = 0; rr < 4; ++rr) {                     \
        float e;                                                             \
        asm("v_exp_f32 %0, %1" : "=v"(e) : "v"(C[t][rr]));                   \
        sum[t][rr] = fmaf(en, e, sum[t][rr]);                                \
      }                                                                      \
    }                                                                        \
  }

  // 1-step register double-buffer (E/O), as the passing v2/v8; residual
  // per-wave latency exposure is covered by co-resident waves.
  bf16x8 e0, e1, o0, o1;
  e0 = *reinterpret_cast<const bf16x8*>(bptr);
  e1 = *reinterpret_cast<const bf16x8*>(bptr + 64);
  o0 = *reinterpret_cast<const bf16x8*>(bptr + 2048);
  o1 = *reinterpret_cast<const bf16x8*>(bptr + 2048 + 64);

  // Peeled steps 0,1 (no FIN for step -1).
  MS(cA, e0, e1)
  e0 = *reinterpret_cast<const bf16x8*>(bptr + 2 * 2048);
  e1 = *reinterpret_cast<const bf16x8*>(bptr + 2 * 2048 + 64);
  MS(cB, o0, o1)
  FIN(cA, enr[0])
  o0 = *reinterpret_cast<const bf16x8*>(bptr + 3 * 2048);
  o1 = *reinterpret_cast<const bf16x8*>(bptr + 3 * 2048 + 64);

  // Steady state: steps 2u,2u+1; loads for 2u+2,2u+3. Final iteration's
  // loads (st 64,65) overread ~5 KB past the s==15 slice into the Em
  // workspace buffer -> benign (same pattern as the passing v2/v8).
  // unroll(disable): an unroll would balloon live ranges (v6: 192 VGPR).
  const char* bp = bptr + 4 * 2048;
#pragma clang loop unroll(disable)
  for (int u = 1; u < TSTEPS / 2; ++u, bp += 2 * 2048) {
    MS(cA, e0, e1)
    FIN(cB, enr[(2 * u - 1) * 16])
    e0 = *reinterpret_cast<const bf16x8*>(bp);
    e1 = *reinterpret_cast<const bf16x8*>(bp + 64);
    MS(cB, o0, o1)
    FIN(cA, enr[(2 * u) * 16])
    o0 = *reinterpret_cast<const bf16x8*>(bp + 2048);
    o1 = *reinterpret_cast<const bf16x8*>(bp + 2048 + 64);
  }
  FIN(cB, enr[(TSTEPS - 1) * 16])
#undef MS
#undef FIN

  // Reduce the 16 n-columns held across lanes of each k-group.
#pragma unroll
  for (int t = 0; t < 2; ++t)
#pragma unroll
    for (int r = 0; r < 4; ++r) {
      float v = sum[t][r];
      v += __shfl_xor(v, 1);
      v += __shfl_xor(v, 2);
      v += __shfl_xor(v, 4);
      v += __shfl_xor(v, 8);
      sum[t][r] = v;
    }
  if (lr == 0) {
#pragma unroll
    for (int t = 0; t < 2; ++t)
#pragma unroll
      for (int r = 0; r < 4; ++r) {
        int row = mbase + t * 16 + lg * 4 + r;
        partials[(size_t)s * M_PTS + row] = sum[t][r];
      }
  }
}

__global__ __launch_bounds__(256) void kde_reduce(
    const float* __restrict__ partials, const float* __restrict__ Em,
    float* __restrict__ out) {
  int m = blockIdx.x * 256 + threadIdx.x;
  float t = 0.0f;
#pragma unroll
  for (int s2 = 0; s2 < NSL; ++s2)
    t += partials[(size_t)s2 * M_PTS + m];
  out[m] = Em[m] * t;
}

extern "C" void kernel_launch(void* const* d_in, const int* in_sizes, int n_in,
                              void* d_out, int out_size, void* d_ws, size_t ws_size,
                              hipStream_t stream) {
  const float* pts = (const float*)d_in[0];   // [M, 64]
  const float* spt = (const float*)d_in[1];   // [N, 64]
  const float* w   = (const float*)d_in[2];   // [N]
  const float* bw  = (const float*)d_in[3];   // scalar
  float* out = (float*)d_out;                 // [M] fp32

  // ws: ptsb 2MB | spb 2MB | Em 64KB | En 64KB | partials 1MB
  // (Em immediately after spb absorbs the benign tail prefetch overread.)
  char* ws = (char*)d_ws;
  unsigned short* ptsb = (unsigned short*)ws;
  unsigned short* spb  = (unsigned short*)(ws + (size_t)M_PTS * DIM * 2);
  float* Em = (float*)(ws + (size_t)(M_PTS + N_SPT) * DIM * 2);
  float* En = Em + M_PTS;
  float* partials = En + N_SPT;

  kde_prep<<<dim3((M_PTS + N_SPT) / 16), 256, 0, stream>>>(
      pts, spt, w, bw, ptsb, spb, Em, En);
  kde_main<<<dim3((M_PTS / MBLK) * NSL), 256, 0, stream>>>(
      ptsb, spb, En, partials);
  kde_reduce<<<dim3(M_PTS / 256), 256, 0, stream>>>(partials, Em, out);
}

// Round 10
// 59.167 us; speedup vs baseline: 2.4133x; 2.4133x over previous
//
#include <hip/hip_runtime.h>
#include <hip/hip_bf16.h>

#define M_PTS 16384
#define N_SPT 16384
#define DIM   64
#define NSL   16                      // n-slices (blockIdx.y)
#define SLN   (N_SPT / NSL)           // 1024 n-rows per slice
#define MBLK  128                     // m-rows per block (4 waves x 32)
#define BUFROWS 64                    // n-rows per stage round
#define BUFBYTES (BUFROWS * DIM * 2)  // 8 KB per buffer
#define ROUNDS (SLN / BUFROWS)        // 16
#define STEPS  (BUFROWS / 16)         // 4 MFMA steps per round

typedef __attribute__((ext_vector_type(8))) short bf16x8;
typedef __attribute__((ext_vector_type(4))) float f32x4;

#define LOG2E 1.4426950408889634f

__device__ __forceinline__ unsigned short f32_bf16_rne(float f) {
  unsigned int x = __float_as_uint(f);
  x = x + 0x7fffu + ((x >> 16) & 1u);
  return (unsigned short)(x >> 16);
}
__device__ __forceinline__ float bf16_f32(unsigned short u) {
  return __uint_as_float(((unsigned int)u) << 16);
}

// Prep (unchanged, known-good):
//  points : store p~ = bf16(scale * p); Em = exp2(-|p~|^2/(2*scale))
//  spatial: store s~ = bf16(s); En = w * exp2(-|s~|^2 * scale/2)
// Em*En*exp2(p~ . s~) == exact Gaussian of the rounded points.
__global__ __launch_bounds__(256) void kde_prep(
    const float* __restrict__ pts, const float* __restrict__ spt,
    const float* __restrict__ w, const float* __restrict__ bw,
    unsigned short* __restrict__ ptsb, unsigned short* __restrict__ spb,
    float* __restrict__ Em, float* __restrict__ En) {
  const float b = bw[0];
  const float scale = LOG2E / (b * b);
  const float c1 = 0.5f * scale;
  const float invc = (b * b) / (2.0f * LOG2E);
  const int tid = threadIdx.x;
  const bool isP = blockIdx.x < (M_PTS / 16);
  const int r0 = isP ? (blockIdx.x * 16) : ((blockIdx.x - M_PTS / 16) * 16);
  const float* __restrict__ src = isP ? pts : spt;
  unsigned short* __restrict__ dst = isP ? ptsb : spb;

  size_t off = (size_t)r0 * DIM + (size_t)tid * 4;
  float4 v = *reinterpret_cast<const float4*>(src + off);
  if (isP) { v.x *= scale; v.y *= scale; v.z *= scale; v.w *= scale; }
  ushort4 u;
  u.x = f32_bf16_rne(v.x); u.y = f32_bf16_rne(v.y);
  u.z = f32_bf16_rne(v.z); u.w = f32_bf16_rne(v.w);
  float ax = bf16_f32(u.x), ay = bf16_f32(u.y);
  float az = bf16_f32(u.z), aw = bf16_f32(u.w);
  float sq = ax * ax + ay * ay + az * az + aw * aw;
  *reinterpret_cast<ushort4*>(dst + off) = u;

  sq += __shfl_xor(sq, 1);
  sq += __shfl_xor(sq, 2);
  sq += __shfl_xor(sq, 4);
  sq += __shfl_xor(sq, 8);
  if ((tid & 15) == 0) {
    int row = r0 + (tid >> 4);
    if (isP) Em[row] = exp2f(-sq * invc);
    else     En[row] = w[row] * exp2f(-sq * c1);
  }
}

// Main v11 = v0's DMA+LDS staging (low vmem traffic: B staged ONCE per
// block via contiguous global_load_lds, then re-read from LDS) combined
// with the halved 32m x 16n wave tile (low VGPR -> 8 blocks/CU).
// v10's lesson: direct-global B reads are a 16-scattered-line gather per
// load instr; doubling waves doubled gather traffic -> 152us at 46%
// occupancy. v0's DMA had 4x less vmem traffic -- staging was never
// overhead, it was the point. What v0 lacked was occupancy (124 VGPR, 36KB
// LDS -> 4 waves/SIMD). This kernel: ~56-reg live set, 20KB LDS
// (2 x 8KB dbuf + 4KB En) -> 8 blocks/CU -> 8 waves/SIMD, with the same
// proven sync structure (STAGE at round top into the idle buffer,
// vmcnt(0)+barrier at round bottom). No reg double-buffer for B: ds_read
// latency is hidden by co-resident waves, and the regs are better spent
// on occupancy. No __launch_bounds__ min-waves cap (3/3 corruption rule).
__global__ __launch_bounds__(256) void kde_main(
    const unsigned short* __restrict__ ptsb,
    const unsigned short* __restrict__ spb,
    const float* __restrict__ En,
    float* __restrict__ partials) {
  __shared__ __align__(16) char ldsb[2 * BUFBYTES];  // 16 KB double buffer
  __shared__ float lden[SLN];                        // 4 KB En slice

  const int tid = threadIdx.x;
  const int lane = tid & 63;
  const int wave = tid >> 6;
  const int lr = lane & 15;   // tile row (A) / tile col (B)
  const int lg = lane >> 4;   // k-group
  const int mbase = blockIdx.x * MBLK + wave * 32;
  const int s = blockIdx.y;

#pragma unroll
  for (int k = 0; k < SLN / 256; ++k)
    lden[tid + k * 256] = En[s * SLN + tid + k * 256];

  // A fragments (read once; 16 VGPRs).
  bf16x8 a[2][2];
#pragma unroll
  for (int t = 0; t < 2; ++t)
#pragma unroll
    for (int h = 0; h < 2; ++h)
      a[t][h] = *reinterpret_cast<const bf16x8*>(
          ptsb + (size_t)(mbase + t * 16 + lr) * DIM + h * 32 + lg * 8);

  // DMA staging: LDS dest wave-uniform (HW adds lane*16); global source
  // per-lane, pre-swizzled within each 1KB chunk (proven v0 pattern).
  // 8 KB per round: 2 chunks per wave x 4 waves.
  const char* gbase = (const char*)spb + (size_t)s * SLN * DIM * 2;
  const int srcswz = ((lane >> 3) & 7) << 4;

#define STAGE(r, c)                                                          \
  {                                                                          \
    const char* g = gbase + (size_t)(r) * BUFBYTES;                          \
    _Pragma("unroll") for (int k = 0; k < 2; ++k) {                          \
      int P = wave * 2048 + k * 1024 + lane * 16;                            \
      char* ldst = ldsb + (c) * BUFBYTES + wave * 2048 + k * 1024;           \
      __builtin_amdgcn_global_load_lds(                                      \
          (const __attribute__((address_space(1))) void*)(g + (P ^ srcswz)), \
          (__attribute__((address_space(3))) void*)ldst, 16, 0, 0);          \
    }                                                                        \
  }

#define MS(C, q0, q1, st)                                                    \
  {                                                                          \
    bf16x8 b0 = *reinterpret_cast<const bf16x8*>((q0) + (st) * 2048);        \
    bf16x8 b1 = *reinterpret_cast<const bf16x8*>((q1) + (st) * 2048);        \
    _Pragma("unroll") for (int t = 0; t < 2; ++t) {                          \
      C[t] = __builtin_amdgcn_mfma_f32_16x16x32_bf16(a[t][0], b0, kz,        \
                                                     0, 0, 0);               \
      C[t] = __builtin_amdgcn_mfma_f32_16x16x32_bf16(a[t][1], b1, C[t],      \
                                                     0, 0, 0);               \
    }                                                                        \
  }

#define FIN(C, EN)                                                           \
  {                                                                          \
    float en = (EN);                                                         \
    _Pragma("unroll") for (int t = 0; t < 2; ++t) {                          \
      _Pragma("unroll") for (int rr = 0; rr < 4; ++rr) {                     \
        float e;                                                             \
        asm("v_exp_f32 %0, %1" : "=v"(e) : "v"(C[t][rr]));                   \
        sum[t][rr] = fmaf(en, e, sum[t][rr]);                                \
      }                                                                      \
    }                                                                        \
  }

  const f32x4 kz = {0.0f, 0.0f, 0.0f, 0.0f};  // shared C-init quad
  float sum[2][4] = {{0.0f, 0.0f, 0.0f, 0.0f}, {0.0f, 0.0f, 0.0f, 0.0f}};
  f32x4 cA[2], cB[2];

  // Swizzled read pointers (b1 = +64 swizzled separately; the st*2048 step
  // stride and the 8K buffer-select bit commute with the XOR on bits 4..6).
  const int swz = (lr & 7) << 4;
  const char* pb0 = ldsb + ((lr * 128 + lg * 16) ^ swz);
  const char* pb1 = ldsb + ((lr * 128 + 64 + lg * 16) ^ swz);

  STAGE(0, 0)
  asm volatile("s_waitcnt vmcnt(0)" ::: "memory");
  __syncthreads();

#pragma clang loop unroll(disable)
  for (int r = 0; r < ROUNDS; ++r) {
    if (r + 1 < ROUNDS) {
      STAGE(r + 1, (r + 1) & 1)   // DMA next round into the idle buffer
    }
    const char* q0 = pb0 + (r & 1) * BUFBYTES;
    const char* q1 = pb1 + (r & 1) * BUFBYTES;
    const float* er = lden + r * BUFROWS + lr;

    MS(cA, q0, q1, 0)
    MS(cB, q0, q1, 1) FIN(cA, er[0 * 16])
    MS(cA, q0, q1, 2) FIN(cB, er[1 * 16])
    MS(cB, q0, q1, 3) FIN(cA, er[2 * 16])
    FIN(cB, er[3 * 16])

    // Staged data for round r+1 must have landed; also fences buffer reuse.
    asm volatile("s_waitcnt vmcnt(0)" ::: "memory");
    __syncthreads();
  }
#undef STAGE
#undef MS
#undef FIN

  // Reduce the 16 n-columns held across lanes of each k-group.
#pragma unroll
  for (int t = 0; t < 2; ++t)
#pragma unroll
    for (int r = 0; r < 4; ++r) {
      float v = sum[t][r];
      v += __shfl_xor(v, 1);
      v += __shfl_xor(v, 2);
      v += __shfl_xor(v, 4);
      v += __shfl_xor(v, 8);
      sum[t][r] = v;
    }
  if (lr == 0) {
#pragma unroll
    for (int t = 0; t < 2; ++t)
#pragma unroll
      for (int r = 0; r < 4; ++r) {
        int row = mbase + t * 16 + lg * 4 + r;
        partials[(size_t)s * M_PTS + row] = sum[t][r];
      }
  }
}

__global__ __launch_bounds__(256) void kde_reduce(
    const float* __restrict__ partials, const float* __restrict__ Em,
    float* __restrict__ out) {
  int m = blockIdx.x * 256 + threadIdx.x;
  float t = 0.0f;
#pragma unroll
  for (int s2 = 0; s2 < NSL; ++s2)
    t += partials[(size_t)s2 * M_PTS + m];
  out[m] = Em[m] * t;
}

extern "C" void kernel_launch(void* const* d_in, const int* in_sizes, int n_in,
                              void* d_out, int out_size, void* d_ws, size_t ws_size,
                              hipStream_t stream) {
  const float* pts = (const float*)d_in[0];   // [M, 64]
  const float* spt = (const float*)d_in[1];   // [N, 64]
  const float* w   = (const float*)d_in[2];   // [N]
  const float* bw  = (const float*)d_in[3];   // scalar
  float* out = (float*)d_out;                 // [M] fp32

  // ws: ptsb 2MB | spb 2MB | Em 64KB | En 64KB | partials 1MB
  char* ws = (char*)d_ws;
  unsigned short* ptsb = (unsigned short*)ws;
  unsigned short* spb  = (unsigned short*)(ws + (size_t)M_PTS * DIM * 2);
  float* Em = (float*)(ws + (size_t)(M_PTS + N_SPT) * DIM * 2);
  float* En = Em + M_PTS;
  float* partials = En + N_SPT;

  kde_prep<<<dim3((M_PTS + N_SPT) / 16), 256, 0, stream>>>(
      pts, spt, w, bw, ptsb, spb, Em, En);
  kde_main<<<dim3(M_PTS / MBLK, NSL), 256, 0, stream>>>(
      ptsb, spb, En, partials);
  kde_reduce<<<dim3(M_PTS / 256), 256, 0, stream>>>(partials, Em, out);
}

// Round 11
// 58.089 us; speedup vs baseline: 2.4581x; 1.0186x over previous
//
#include <hip/hip_runtime.h>
#include <hip/hip_bf16.h>

#define M_PTS 16384
#define N_SPT 16384
#define DIM   64
#define NSL   16                      // n-slices (blockIdx.y)
#define SLN   (N_SPT / NSL)           // 1024 n-rows per slice
#define MBLK  128                     // m-rows per block (4 waves x 32)
#define BUFROWS 64                    // n-rows per stage round
#define BUFBYTES (BUFROWS * DIM * 2)  // 8 KB per buffer
#define ROUNDS (SLN / BUFROWS)        // 16
#define STEPS  (BUFROWS / 16)         // 4 MFMA steps per round

typedef __attribute__((ext_vector_type(8))) short bf16x8;
typedef __attribute__((ext_vector_type(4))) float f32x4;

#define LOG2E 1.4426950408889634f

__device__ __forceinline__ unsigned short f32_bf16_rne(float f) {
  unsigned int x = __float_as_uint(f);
  x = x + 0x7fffu + ((x >> 16) & 1u);
  return (unsigned short)(x >> 16);
}
__device__ __forceinline__ float bf16_f32(unsigned short u) {
  return __uint_as_float(((unsigned int)u) << 16);
}

// Prep (unchanged, known-good):
//  points : store p~ = bf16(scale * p); Em = exp2(-|p~|^2/(2*scale))
//  spatial: store s~ = bf16(s); En = w * exp2(-|s~|^2 * scale/2)
// Em*En*exp2(p~ . s~) == exact Gaussian of the rounded points.
__global__ __launch_bounds__(256) void kde_prep(
    const float* __restrict__ pts, const float* __restrict__ spt,
    const float* __restrict__ w, const float* __restrict__ bw,
    unsigned short* __restrict__ ptsb, unsigned short* __restrict__ spb,
    float* __restrict__ Em, float* __restrict__ En) {
  const float b = bw[0];
  const float scale = LOG2E / (b * b);
  const float c1 = 0.5f * scale;
  const float invc = (b * b) / (2.0f * LOG2E);
  const int tid = threadIdx.x;
  const bool isP = blockIdx.x < (M_PTS / 16);
  const int r0 = isP ? (blockIdx.x * 16) : ((blockIdx.x - M_PTS / 16) * 16);
  const float* __restrict__ src = isP ? pts : spt;
  unsigned short* __restrict__ dst = isP ? ptsb : spb;

  size_t off = (size_t)r0 * DIM + (size_t)tid * 4;
  float4 v = *reinterpret_cast<const float4*>(src + off);
  if (isP) { v.x *= scale; v.y *= scale; v.z *= scale; v.w *= scale; }
  ushort4 u;
  u.x = f32_bf16_rne(v.x); u.y = f32_bf16_rne(v.y);
  u.z = f32_bf16_rne(v.z); u.w = f32_bf16_rne(v.w);
  float ax = bf16_f32(u.x), ay = bf16_f32(u.y);
  float az = bf16_f32(u.z), aw = bf16_f32(u.w);
  float sq = ax * ax + ay * ay + az * az + aw * aw;
  *reinterpret_cast<ushort4*>(dst + off) = u;

  sq += __shfl_xor(sq, 1);
  sq += __shfl_xor(sq, 2);
  sq += __shfl_xor(sq, 4);
  sq += __shfl_xor(sq, 8);
  if ((tid & 15) == 0) {
    int row = r0 + (tid >> 4);
    if (isP) Em[row] = exp2f(-sq * invc);
    else     En[row] = w[row] * exp2f(-sq * c1);
  }
}

// Main v12 = v11 (55.6us: DMA+LDS staging, 32m x 16n wave tile, 44 VGPR,
// 8 blocks/CU) + three zero-risk scheduling tweaks:
//  a) s_setprio(1/0) around each MFMA cluster (T5) -- our regime (8
//     independent blocks/CU, no inter-block lockstep) matches the
//     attention case where it measured +4-7%, not the lockstep-GEMM null.
//  b) Per-round En scalars hoisted to the round top: their ds_read
//     latency overlaps the MFMA steps instead of sitting inline in FIN.
//  c) unroll_count(2) on the round loop: const-folds the (r&1) buffer
//     selects and lets the scheduler pipeline across a round pair.
//     Bounded growth from a 44-reg body; no min-waves cap (3/3 rule).
__global__ __launch_bounds__(256) void kde_main(
    const unsigned short* __restrict__ ptsb,
    const unsigned short* __restrict__ spb,
    const float* __restrict__ En,
    float* __restrict__ partials) {
  __shared__ __align__(16) char ldsb[2 * BUFBYTES];  // 16 KB double buffer
  __shared__ float lden[SLN];                        // 4 KB En slice

  const int tid = threadIdx.x;
  const int lane = tid & 63;
  const int wave = tid >> 6;
  const int lr = lane & 15;   // tile row (A) / tile col (B)
  const int lg = lane >> 4;   // k-group
  const int mbase = blockIdx.x * MBLK + wave * 32;
  const int s = blockIdx.y;

#pragma unroll
  for (int k = 0; k < SLN / 256; ++k)
    lden[tid + k * 256] = En[s * SLN + tid + k * 256];

  // A fragments (read once; 16 VGPRs).
  bf16x8 a[2][2];
#pragma unroll
  for (int t = 0; t < 2; ++t)
#pragma unroll
    for (int h = 0; h < 2; ++h)
      a[t][h] = *reinterpret_cast<const bf16x8*>(
          ptsb + (size_t)(mbase + t * 16 + lr) * DIM + h * 32 + lg * 8);

  // DMA staging: LDS dest wave-uniform (HW adds lane*16); global source
  // per-lane, pre-swizzled within each 1KB chunk (proven v0 pattern).
  const char* gbase = (const char*)spb + (size_t)s * SLN * DIM * 2;
  const int srcswz = ((lane >> 3) & 7) << 4;

#define STAGE(r, c)                                                          \
  {                                                                          \
    const char* g = gbase + (size_t)(r) * BUFBYTES;                          \
    _Pragma("unroll") for (int k = 0; k < 2; ++k) {                          \
      int P = wave * 2048 + k * 1024 + lane * 16;                            \
      char* ldst = ldsb + (c) * BUFBYTES + wave * 2048 + k * 1024;           \
      __builtin_amdgcn_global_load_lds(                                      \
          (const __attribute__((address_space(1))) void*)(g + (P ^ srcswz)), \
          (__attribute__((address_space(3))) void*)ldst, 16, 0, 0);          \
    }                                                                        \
  }

#define MS(C, q0, q1, st)                                                    \
  {                                                                          \
    bf16x8 b0 = *reinterpret_cast<const bf16x8*>((q0) + (st) * 2048);        \
    bf16x8 b1 = *reinterpret_cast<const bf16x8*>((q1) + (st) * 2048);        \
    __builtin_amdgcn_s_setprio(1);                                           \
    _Pragma("unroll") for (int t = 0; t < 2; ++t) {                          \
      C[t] = __builtin_amdgcn_mfma_f32_16x16x32_bf16(a[t][0], b0, kz,        \
                                                     0, 0, 0);               \
      C[t] = __builtin_amdgcn_mfma_f32_16x16x32_bf16(a[t][1], b1, C[t],      \
                                                     0, 0, 0);               \
    }                                                                        \
    __builtin_amdgcn_s_setprio(0);                                           \
  }

#define FIN(C, EN)                                                           \
  {                                                                          \
    float en = (EN);                                                         \
    _Pragma("unroll") for (int t = 0; t < 2; ++t) {                          \
      _Pragma("unroll") for (int rr = 0; rr < 4; ++rr) {                     \
        float e;                                                             \
        asm("v_exp_f32 %0, %1" : "=v"(e) : "v"(C[t][rr]));                   \
        sum[t][rr] = fmaf(en, e, sum[t][rr]);                                \
      }                                                                      \
    }                                                                        \
  }

  const f32x4 kz = {0.0f, 0.0f, 0.0f, 0.0f};  // shared C-init quad
  float sum[2][4] = {{0.0f, 0.0f, 0.0f, 0.0f}, {0.0f, 0.0f, 0.0f, 0.0f}};
  f32x4 cA[2], cB[2];

  // Swizzled read pointers (b1 = +64 swizzled separately; the st*2048 step
  // stride and the 8K buffer-select bit commute with the XOR on bits 4..6).
  const int swz = (lr & 7) << 4;
  const char* pb0 = ldsb + ((lr * 128 + lg * 16) ^ swz);
  const char* pb1 = ldsb + ((lr * 128 + 64 + lg * 16) ^ swz);

  STAGE(0, 0)
  asm volatile("s_waitcnt vmcnt(0)" ::: "memory");
  __syncthreads();

#pragma clang loop unroll_count(2)
  for (int r = 0; r < ROUNDS; ++r) {
    if (r + 1 < ROUNDS) {
      STAGE(r + 1, (r + 1) & 1)   // DMA next round into the idle buffer
    }
    const char* q0 = pb0 + (r & 1) * BUFBYTES;
    const char* q1 = pb1 + (r & 1) * BUFBYTES;
    const float* er = lden + r * BUFROWS + lr;

    // En scalars for the whole round, issued before the MFMA steps so
    // their LDS latency hides under compute.
    float en0 = er[0 * 16];
    float en1 = er[1 * 16];
    float en2 = er[2 * 16];
    float en3 = er[3 * 16];

    MS(cA, q0, q1, 0)
    MS(cB, q0, q1, 1) FIN(cA, en0)
    MS(cA, q0, q1, 2) FIN(cB, en1)
    MS(cB, q0, q1, 3) FIN(cA, en2)
    FIN(cB, en3)

    // Staged data for round r+1 must have landed; also fences buffer reuse.
    asm volatile("s_waitcnt vmcnt(0)" ::: "memory");
    __syncthreads();
  }
#undef STAGE
#undef MS
#undef FIN

  // Reduce the 16 n-columns held across lanes of each k-group.
#pragma unroll
  for (int t = 0; t < 2; ++t)
#pragma unroll
    for (int r = 0; r < 4; ++r) {
      float v = sum[t][r];
      v += __shfl_xor(v, 1);
      v += __shfl_xor(v, 2);
      v += __shfl_xor(v, 4);
      v += __shfl_xor(v, 8);
      sum[t][r] = v;
    }
  if (lr == 0) {
#pragma unroll
    for (int t = 0; t < 2; ++t)
#pragma unroll
      for (int r = 0; r < 4; ++r) {
        int row = mbase + t * 16 + lg * 4 + r;
        partials[(size_t)s * M_PTS + row] = sum[t][r];
      }
  }
}

__global__ __launch_bounds__(256) void kde_reduce(
    const float* __restrict__ partials, const float* __restrict__ Em,
    float* __restrict__ out) {
  int m = blockIdx.x * 256 + threadIdx.x;
  float t = 0.0f;
#pragma unroll
  for (int s2 = 0; s2 < NSL; ++s2)
    t += partials[(size_t)s2 * M_PTS + m];
  out[m] = Em[m] * t;
}

extern "C" void kernel_launch(void* const* d_in, const int* in_sizes, int n_in,
                              void* d_out, int out_size, void* d_ws, size_t ws_size,
                              hipStream_t stream) {
  const float* pts = (const float*)d_in[0];   // [M, 64]
  const float* spt = (const float*)d_in[1];   // [N, 64]
  const float* w   = (const float*)d_in[2];   // [N]
  const float* bw  = (const float*)d_in[3];   // scalar
  float* out = (float*)d_out;                 // [M] fp32

  // ws: ptsb 2MB | spb 2MB | Em 64KB | En 64KB | partials 1MB
  char* ws = (char*)d_ws;
  unsigned short* ptsb = (unsigned short*)ws;
  unsigned short* spb  = (unsigned short*)(ws + (size_t)M_PTS * DIM * 2);
  float* Em = (float*)(ws + (size_t)(M_PTS + N_SPT) * DIM * 2);
  float* En = Em + M_PTS;
  float* partials = En + N_SPT;

  kde_prep<<<dim3((M_PTS + N_SPT) / 16), 256, 0, stream>>>(
      pts, spt, w, bw, ptsb, spb, Em, En);
  kde_main<<<dim3(M_PTS / MBLK, NSL), 256, 0, stream>>>(
      ptsb, spb, En, partials);
  kde_reduce<<<dim3(M_PTS / 256), 256, 0, stream>>>(partials, Em, out);
}